// Round 8
// baseline (52.324 us; speedup 1.0000x reference)
//
#include <hip/hip_runtime.h>
#include <hip/hip_bf16.h>

#define M_DIM 4096
#define N_DIM 4096
#define K_DIM 1024
#define NT (K_DIM / 64)   // 16 K-tiles of BK=64

typedef short short8 __attribute__((ext_vector_type(8)));
typedef unsigned short ushort8 __attribute__((ext_vector_type(8)));
typedef unsigned short ushort4v __attribute__((ext_vector_type(4)));
typedef float f32x4 __attribute__((ext_vector_type(4)));

// fp32 -> bf16 round-to-nearest-even (bias-free over the K-sum)
__device__ __forceinline__ unsigned short f2bf_rne(float f) {
    union { float f; unsigned u; } v;
    v.f = f;
    unsigned u = v.u;
    u += 0x7FFFu + ((u >> 16) & 1u);
    return (unsigned short)(u >> 16);
}

// async global->LDS, 16B/lane. LDS dest = wave-uniform base + lane*16.
__device__ __forceinline__ void gload16(const void* g, void* l) {
    __builtin_amdgcn_global_load_lds(
        (const __attribute__((address_space(1))) void*)g,
        (__attribute__((address_space(3))) void*)l,
        16, 0, 0);
}

// ---- merged conversion ----
// blocks 0..2047:    A fp32 -> bf16 (same M x K layout)
// blocks 2048..3071: B fp32 (K x N) -> Bp: FRAGMENT-PACKED B^T. frag(n16,k32) is
//   1KB contiguous; elem lane*8 holds B^T[n0+(lane&15)][k0+(lane>>4)*8 .. +7],
//   i.e. exactly the mfma_16x16x32 B-operand register image.
__global__ __launch_bounds__(256) void cvt_kernel(const float* __restrict__ A,
                                                  const float* __restrict__ B,
                                                  unsigned short* __restrict__ Aw,
                                                  unsigned short* __restrict__ Bp) {
    __shared__ unsigned short tile[64][68];   // [k][n], +4 pad
    if (blockIdx.x < 2048) {
        size_t i = (size_t)blockIdx.x * 256 + threadIdx.x;
        const float4* s = (const float4*)A + i * 2;
        float4 v0 = s[0], v1 = s[1];
        ushort8 o;
        o[0] = f2bf_rne(v0.x); o[1] = f2bf_rne(v0.y);
        o[2] = f2bf_rne(v0.z); o[3] = f2bf_rne(v0.w);
        o[4] = f2bf_rne(v1.x); o[5] = f2bf_rne(v1.y);
        o[6] = f2bf_rne(v1.z); o[7] = f2bf_rne(v1.w);
        *(ushort8*)(Aw + i * 8) = o;
    } else {
        int bb = blockIdx.x - 2048;               // 0..1023
        int bn = bb & 63, bk = bb >> 6;           // 64 n-tiles x 16 k-tiles (64x64 each)
        int n0 = bn * 64, k0 = bk * 64;
        int kr = threadIdx.x >> 4;                // 0..15
        int nc = threadIdx.x & 15;
#pragma unroll
        for (int p = 0; p < 4; ++p) {
            int k = kr + p * 16;
            float4 v = *(const float4*)&B[(size_t)(k0 + k) * N_DIM + n0 + nc * 4];
            ushort4v u;
            u[0] = f2bf_rne(v.x); u[1] = f2bf_rne(v.y);
            u[2] = f2bf_rne(v.z); u[3] = f2bf_rne(v.w);
            *(ushort4v*)&tile[k][nc * 4] = u;
        }
        __syncthreads();
        // packed store: this thread covers (n = kr+p*16, k-chunk = nc*4 .. +3)
        int s = (nc >> 1) & 3;                    // k-slot within frag = (k&31)>>3
        int kb = bk * 2 + (nc >> 3);              // global k32-block index
#pragma unroll
        for (int p = 0; p < 4; ++p) {
            int n = kr + p * 16;
            ushort4v o;
#pragma unroll
            for (int j = 0; j < 4; ++j) o[j] = tile[nc * 4 + j][n];
            size_t fb = ((size_t)((n0 + n) >> 4) * (K_DIM / 32) + kb) * 512;
            *(ushort4v*)&Bp[fb + (size_t)((n & 15) + 16 * s) * 8 + (nc & 1) * 4] = o;
        }
    }
}

// ---- 256x256x64 GEMM: A via LDS dbuf (XOR swizzle), B via packed global frags ----
// 8 waves (2Mx4N), per-wave 128x64 = acc[8][4]. LDS = 2 x 32KB (A only).
// Per tile: STG4 A(t+1) -> SB0 -> 8 coalesced 1KB B-frag loads (t+1, ping-pong
// regs, compiler-tracked vmcnt) -> 8 q-steps {2 ds_read, 8 MFMA} free-running ->
// vmcnt(8) (A resident; B may fly) -> barrier. ONE barrier per K-tile.
__global__ __launch_bounds__(512, 2) void gemm8_kernel(const unsigned short* __restrict__ A,
                                                       const unsigned short* __restrict__ Bp,
                                                       float* __restrict__ C) {
    __shared__ __align__(16) unsigned short sA[2][256 * 64];   // 64 KiB

    // XCD-aware bijective swizzle: 256 blocks, 8 XCDs, 32 tiles/XCD (2 rows x 16 cols)
    int bid = blockIdx.x;
    int xcd = bid & 7, ii = bid >> 3;
    int tm = xcd * 2 + (ii & 1);
    int tn = ii >> 1;
    int bM = tm * 256, bN = tn * 256;

    int tid = threadIdx.x;
    int wid = tid >> 6, lane = tid & 63;
    int wm = wid >> 2, wn = wid & 3;

    // A staging (gload_lds, linear dest + inverse-swizzled source)
    int srow = lane >> 3;
    int cslot = (lane & 7) ^ srow;
    const unsigned short* gA = A + (size_t)(bM + wid * 8 + srow) * K_DIM + cslot * 8;

#define STG4(buf, kt)                                                                  \
    _Pragma("unroll") for (int u = 0; u < 4; ++u)                                      \
        gload16(gA + (size_t)(u) * 64 * K_DIM + (size_t)(kt) * 64,                     \
                (char*)&sA[(buf)][0] + (u) * 8192 + wid * 1024);

    // B packed-fragment loads (1KB contiguous per wave-frag)
    size_t nbase = (size_t)(bN >> 4) + wn * 4;
    const unsigned short* gBp = Bp + lane * 8;

#define BV4(BV, kt, KK)                                                                \
    _Pragma("unroll") for (int n = 0; n < 4; ++n)                                      \
        BV[n][KK] = *(const short8*)(gBp +                                             \
            ((nbase + n) * (K_DIM / 32) + (size_t)(kt) * 2 + (KK)) * 512);

    // A fragment reads from LDS (16B-slot XOR swizzle)
    int rA = wm * 128 + (lane & 15);
    int rslot = lane >> 4;
    int l7 = lane & 7;
#define LDA(buf, m, k) \
    (*(const short8*)&sA[(buf)][(rA + (m) * 16) * 64 + ((((k) * 4 + rslot) ^ l7) * 8)])

#define RD_AV(AV, BUF, MB, KK)                 \
    AV[0] = LDA(BUF, (MB), KK);                \
    AV[1] = LDA(BUF, (MB) + 1, KK);

#define MFMAQ(AV, BV, MB, KK)                                                          \
    __builtin_amdgcn_s_setprio(1);                                                     \
    _Pragma("unroll") for (int m2 = 0; m2 < 2; ++m2)                                   \
        _Pragma("unroll") for (int n = 0; n < 4; ++n)                                  \
            acc[(MB) + m2][n] = __builtin_amdgcn_mfma_f32_16x16x32_bf16(               \
                AV[m2], BV[n][KK], acc[(MB) + m2][n], 0, 0, 0);                        \
    __builtin_amdgcn_s_setprio(0);

    f32x4 acc[8][4];
#pragma unroll
    for (int m = 0; m < 8; ++m)
#pragma unroll
        for (int n = 0; n < 4; ++n)
            acc[m][n] = (f32x4){0.f, 0.f, 0.f, 0.f};

    short8 avP[2], avQ[2];        // A m-pair ping-pong
    short8 bvP[4][2], bvQ[4][2];  // B frag sets, per-tile ping-pong

#define SB0 __builtin_amdgcn_sched_barrier(0);

    // one K-tile; avP holds (CB, m0-1, k0) on entry, leaves avP = (NB, m0-1, k0)
#define TILE(t, CB, NB, BVC, BVN)                                                      \
    {                                                                                  \
        STG4(NB, (t) + 1)                                                              \
        SB0                                                                            \
        BV4(BVN, (t) + 1, 0)                                                           \
        BV4(BVN, (t) + 1, 1)                                                           \
        SB0                                                                            \
        RD_AV(avQ, CB, 2, 0) MFMAQ(avP, BVC, 0, 0)                                     \
        RD_AV(avP, CB, 4, 0) MFMAQ(avQ, BVC, 2, 0)                                     \
        RD_AV(avQ, CB, 6, 0) MFMAQ(avP, BVC, 4, 0)                                     \
        RD_AV(avP, CB, 0, 1) MFMAQ(avQ, BVC, 6, 0)                                     \
        RD_AV(avQ, CB, 2, 1) MFMAQ(avP, BVC, 0, 1)                                     \
        RD_AV(avP, CB, 4, 1) MFMAQ(avQ, BVC, 2, 1)                                     \
        RD_AV(avQ, CB, 6, 1) MFMAQ(avP, BVC, 4, 1)                                     \
        RD_AV(avP, NB, 0, 0) MFMAQ(avQ, BVC, 6, 1)                                     \
        asm volatile("s_waitcnt vmcnt(8)" ::: "memory");                               \
        SB0                                                                            \
        __builtin_amdgcn_s_barrier();                                                  \
        SB0                                                                            \
    }

    // ---- prologue: stage tile0 A + load tile0 B frags ----
    STG4(0, 0)
    SB0
    BV4(bvP, 0, 0)
    BV4(bvP, 0, 1)
    SB0
    asm volatile("s_waitcnt vmcnt(8)" ::: "memory");  // A(t0) resident
    SB0
    __builtin_amdgcn_s_barrier();
    SB0
    RD_AV(avP, 0, 0, 0)

#pragma unroll 1
    for (int t = 0; t < NT - 2; t += 2) {
        TILE(t, 0, 1, bvP, bvQ)
        TILE(t + 1, 1, 0, bvQ, bvP)
    }
    TILE(NT - 2, 0, 1, bvP, bvQ)

    // ---- last tile (buf 1, bvQ): no barriers, fused C stores ----
    {
        size_t crow = (size_t)bM + wm * 128 + ((lane >> 4) << 2);
        int ccol = bN + wn * 64 + (lane & 15);
#define ST2(MB)                                                                        \
        _Pragma("unroll") for (int m2 = 0; m2 < 2; ++m2)                               \
            _Pragma("unroll") for (int n = 0; n < 4; ++n)                              \
                _Pragma("unroll") for (int r = 0; r < 4; ++r)                          \
                    C[(crow + ((MB) + m2) * 16 + r) * N_DIM + ccol + n * 16] =         \
                        acc[(MB) + m2][n][r];
        RD_AV(avQ, 1, 2, 0) MFMAQ(avP, bvQ, 0, 0)
        RD_AV(avP, 1, 4, 0) MFMAQ(avQ, bvQ, 2, 0)
        RD_AV(avQ, 1, 6, 0) MFMAQ(avP, bvQ, 4, 0)
        RD_AV(avP, 1, 0, 1) MFMAQ(avQ, bvQ, 6, 0)
        RD_AV(avQ, 1, 2, 1) MFMAQ(avP, bvQ, 0, 1) ST2(0)
        RD_AV(avP, 1, 4, 1) MFMAQ(avQ, bvQ, 2, 1) ST2(2)
        RD_AV(avQ, 1, 6, 1) MFMAQ(avP, bvQ, 4, 1) ST2(4)
        MFMAQ(avQ, bvQ, 6, 1) ST2(6)
#undef ST2
    }
#undef STG4
#undef BV4
#undef LDA
#undef RD_AV
#undef MFMAQ
#undef SB0
#undef TILE
}

// ---- fallback: plain fp32 tiled GEMM (only if ws too small; exact) ----
__global__ __launch_bounds__(256) void sgemm_fb(const float* __restrict__ A,
                                                const float* __restrict__ B,
                                                float* __restrict__ C) {
    __shared__ float sA[64][17];
    __shared__ float sB[16][65];
    int tx = threadIdx.x, ty = threadIdx.y;
    int bM = blockIdx.y * 64, bN = blockIdx.x * 64;
    int t = ty * 16 + tx;
    float acc[4][4] = {};
    for (int k0 = 0; k0 < K_DIM; k0 += 16) {
        __syncthreads();
#pragma unroll
        for (int e = 0; e < 4; ++e) {
            int idx = t * 4 + e;
            int r = idx >> 4, c = idx & 15;
            sA[r][c] = A[(size_t)(bM + r) * K_DIM + k0 + c];
            int r2 = idx >> 6, c2 = idx & 63;
            sB[r2][c2] = B[(size_t)(k0 + r2) * N_DIM + bN + c2];
        }
        __syncthreads();
#pragma unroll
        for (int k = 0; k < 16; ++k) {
            float ar[4], br[4];
#pragma unroll
            for (int q = 0; q < 4; ++q) { ar[q] = sA[ty * 4 + q][k]; br[q] = sB[k][tx * 4 + q]; }
#pragma unroll
            for (int q = 0; q < 4; ++q)
#pragma unroll
                for (int w = 0; w < 4; ++w)
                    acc[q][w] += ar[q] * br[w];
        }
    }
#pragma unroll
    for (int q = 0; q < 4; ++q)
#pragma unroll
        for (int w = 0; w < 4; ++w)
            C[(size_t)(bM + ty * 4 + q) * N_DIM + bN + tx * 4 + w] = acc[q][w];
}

extern "C" void kernel_launch(void* const* d_in, const int* in_sizes, int n_in,
                              void* d_out, int out_size, void* d_ws, size_t ws_size,
                              hipStream_t stream) {
    const float* A = (const float*)d_in[0];
    const float* B = (const float*)d_in[1];
    float* C = (float*)d_out;

    size_t needA = (size_t)M_DIM * K_DIM * sizeof(unsigned short);
    size_t needB = (size_t)K_DIM * N_DIM * sizeof(unsigned short);

    if (ws_size >= needA + needB) {
        unsigned short* Aw = (unsigned short*)d_ws;
        unsigned short* Bw = Aw + (size_t)M_DIM * K_DIM;
        cvt_kernel<<<2048 + 1024, 256, 0, stream>>>(A, B, Aw, Bw);
        gemm8_kernel<<<(M_DIM / 256) * (N_DIM / 256), 512, 0, stream>>>(Aw, Bw, C);
    } else {
        sgemm_fb<<<dim3(N_DIM / 64, M_DIM / 64), dim3(16, 16), 0, stream>>>(A, B, C);
    }
}